// Round 2
// baseline (485.436 us; speedup 1.0000x reference)
//
#include <hip/hip_runtime.h>
#include <math.h>

namespace {

constexpr int KK = 4;
constexpr int DD = 16;
constexpr int BLOCK = 256;
constexpr int PTS = 4;                       // points per thread
constexpr int ROWS_PER_BLOCK = BLOCK * PTS;  // 1024
constexpr int TAB_LINV = 0;                  // KK*DD*DD = 1024 floats
constexpr int TAB_W    = KK * DD * DD;       // + KK*DD = 64 floats
constexpr int TAB_C0   = TAB_W + KK * DD;    // + KK floats
constexpr int TAB_SIZE = TAB_C0 + KK;        // 1092 floats
constexpr float LOG2PI = 1.8378770664093453f;

// ---------------------------------------------------------------------------
// Setup kernel: one block, 64 threads. Inverts the 4 upper-triangular 16x16
// factors, computes w_k = Linv_k * mu_k and c0_k, writes the 1092-float table
// to d_ws. Runs once per launch (~2 us) instead of once per block.
// ---------------------------------------------------------------------------
__global__ __launch_bounds__(64)
void gmm_setup(const float* __restrict__ phi, const float* __restrict__ mu,
               const float* __restrict__ L, float* __restrict__ tab)
{
    __shared__ float sLinv[KK][DD][DD];
    const int tid = threadIdx.x;          // 0..63
    const int k = tid >> 4;
    const int j = tid & 15;

    // column j of Linv_k via back substitution (U x = e_j)
    {
        const float* Lk = L + k * DD * DD;
        float xv[DD];
        #pragma unroll
        for (int m = 0; m < DD; ++m) xv[m] = 0.0f;
        #pragma unroll
        for (int i = DD - 1; i >= 0; --i) {
            float s = (i == j) ? 1.0f : 0.0f;
            #pragma unroll
            for (int m = i + 1; m < DD; ++m)
                s -= Lk[i * DD + m] * xv[m];
            xv[i] = (i <= j) ? (s / Lk[i * DD + i]) : 0.0f;
        }
        #pragma unroll
        for (int i = 0; i < DD; ++i) {
            sLinv[k][i][j] = xv[i];
            tab[TAB_LINV + k * DD * DD + i * DD + j] = xv[i];
        }
    }
    __syncthreads();

    // w_k[i] = sum_j Linv_k[i][j] * mu_k[j]   (thread = (k,i))
    {
        const int i = j;
        float w = 0.0f;
        #pragma unroll
        for (int jj = 0; jj < DD; ++jj)
            w += sLinv[k][i][jj] * mu[k * DD + jj];
        tab[TAB_W + k * DD + i] = w;
    }

    if (tid < KK) {
        float logdet = 0.0f;
        #pragma unroll
        for (int i = 0; i < DD; ++i)
            logdet += logf(L[tid * DD * DD + i * DD + i]);
        tab[TAB_C0 + tid] = logf(phi[tid]) - 8.0f * LOG2PI - logdet;
    }
}

// ---------------------------------------------------------------------------
// Main kernel: copy table to LDS, then pure FMA + LSE. Thread t of a block
// handles rows blockBase + t + 256*p (p=0..3) -> 64-B lane stride loads,
// perfectly coalesced dword stores.
// ---------------------------------------------------------------------------
__global__ __launch_bounds__(BLOCK)
void gmm_energy(const float* __restrict__ z, const float* __restrict__ tab,
                float* __restrict__ out, int N)
{
    __shared__ float sTab[TAB_SIZE];
    const int tid = threadIdx.x;

    for (int idx = tid; idx < TAB_SIZE; idx += BLOCK)
        sTab[idx] = tab[idx];
    __syncthreads();

    const float* sLinv = sTab + TAB_LINV;   // [k][i][j]
    const float* sW    = sTab + TAB_W;      // [k][i]
    const float* sC0   = sTab + TAB_C0;     // [k]

    const int blockBase = blockIdx.x * ROWS_PER_BLOCK;
    const bool full = (blockBase + ROWS_PER_BLOCK) <= N;

    // ---- load PTS rows, lane stride 64 B ----
    float zr[PTS][DD];
    if (full) {
        #pragma unroll
        for (int p = 0; p < PTS; ++p) {
            const int row = blockBase + p * BLOCK + tid;
            const float4* zp = reinterpret_cast<const float4*>(z + (size_t)row * DD);
            #pragma unroll
            for (int c = 0; c < 4; ++c) {
                float4 v = zp[c];
                zr[p][c * 4 + 0] = v.x;
                zr[p][c * 4 + 1] = v.y;
                zr[p][c * 4 + 2] = v.z;
                zr[p][c * 4 + 3] = v.w;
            }
        }
    } else {
        #pragma unroll
        for (int p = 0; p < PTS; ++p) {
            const int row = blockBase + p * BLOCK + tid;
            if (row < N) {
                const float4* zp = reinterpret_cast<const float4*>(z + (size_t)row * DD);
                #pragma unroll
                for (int c = 0; c < 4; ++c) {
                    float4 v = zp[c];
                    zr[p][c * 4 + 0] = v.x;
                    zr[p][c * 4 + 1] = v.y;
                    zr[p][c * 4 + 2] = v.z;
                    zr[p][c * 4 + 3] = v.w;
                }
            } else {
                #pragma unroll
                for (int d = 0; d < DD; ++d) zr[p][d] = 0.0f;
            }
        }
    }

    // ---- per-component Mahalanobis via triangular matvec ----
    float lg[PTS][KK];
    #pragma unroll
    for (int k = 0; k < KK; ++k) {
        float q[PTS];
        #pragma unroll
        for (int p = 0; p < PTS; ++p) q[p] = 0.0f;
        #pragma unroll
        for (int i = 0; i < DD; ++i) {
            const float wk = sW[k * DD + i];
            float acc[PTS];
            #pragma unroll
            for (int p = 0; p < PTS; ++p) acc[p] = -wk;
            #pragma unroll
            for (int j = i; j < DD; ++j) {
                const float cf = sLinv[k * DD * DD + i * DD + j]; // uniform broadcast
                #pragma unroll
                for (int p = 0; p < PTS; ++p)
                    acc[p] = fmaf(cf, zr[p][j], acc[p]);
            }
            #pragma unroll
            for (int p = 0; p < PTS; ++p)
                q[p] = fmaf(acc[p], acc[p], q[p]);
        }
        const float c0 = sC0[k];
        #pragma unroll
        for (int p = 0; p < PTS; ++p)
            lg[p][k] = fmaf(-0.5f, q[p], c0);
    }

    // ---- logsumexp over K=4, negate, store (coalesced dword stores) ----
    #pragma unroll
    for (int p = 0; p < PTS; ++p) {
        float m01 = fmaxf(lg[p][0], lg[p][1]);
        float m23 = fmaxf(lg[p][2], lg[p][3]);
        float m = fmaxf(m01, m23);
        float s = __expf(lg[p][0] - m) + __expf(lg[p][1] - m)
                + __expf(lg[p][2] - m) + __expf(lg[p][3] - m);
        float e = -(m + __logf(s));
        const int row = blockBase + p * BLOCK + tid;
        if (full || row < N) out[row] = e;
    }
}

} // namespace

extern "C" void kernel_launch(void* const* d_in, const int* in_sizes, int n_in,
                              void* d_out, int out_size, void* d_ws, size_t ws_size,
                              hipStream_t stream) {
    const float* z   = (const float*)d_in[0];   // [N,16]
    const float* phi = (const float*)d_in[1];   // [4]
    const float* mu  = (const float*)d_in[2];   // [4,16]
    const float* L   = (const float*)d_in[3];   // [4,16,16] upper-triangular
    float* out = (float*)d_out;                 // [N]
    float* tab = (float*)d_ws;                  // 1092-float table
    const int N = in_sizes[0] / DD;

    gmm_setup<<<1, 64, 0, stream>>>(phi, mu, L, tab);
    const int grid = (N + ROWS_PER_BLOCK - 1) / ROWS_PER_BLOCK;
    gmm_energy<<<grid, BLOCK, 0, stream>>>(z, tab, out, N);
}